// Round 22
// baseline (379.861 us; speedup 1.0000x reference)
//
#include <hip/hip_runtime.h>
#include <math.h>

#define LR_C 0.1f
#define WINDOW_C 10
#define NH 512
#define WAVE 64
#define ALPHA (-1.44269504088896340736f)  // -log2(e)
#define NSEG 500
#define KN 6   // Newton updates; NSEG=250 calib: KN=4 -> 0.080 FAIL, KN=6 -> floor

typedef _Float16 half_t;
typedef __fp16 fp16x2_t __attribute__((ext_vector_type(2)));

__device__ __forceinline__ void gld_lds16(const void* g, void* l) {
    __builtin_amdgcn_global_load_lds((const __attribute__((address_space(1))) void*)g,
                                     (__attribute__((address_space(3))) void*)l, 16, 0, 0);
}
__device__ __forceinline__ void gld_lds4(const void* g, void* l) {
    __builtin_amdgcn_global_load_lds((const __attribute__((address_space(1))) void*)g,
                                     (__attribute__((address_space(3))) void*)l, 4, 0, 0);
}
__device__ __forceinline__ unsigned pack_h2(float a, float b) {
    union { fp16x2_t h; unsigned u; } c;
    c.h = __builtin_amdgcn_cvt_pkrtz(a, b);
    return c.u;
}
__device__ __forceinline__ unsigned pkadd(unsigned a, unsigned b) {
    union { fp16x2_t h; unsigned u; } x, y;
    x.u = a; y.u = b;
    x.h = x.h + y.h;   // v_pk_add_f16
    return x.u;
}
__device__ __forceinline__ float lo_h(unsigned u) {
    union { unsigned short s; half_t h; } c; c.s = (unsigned short)(u & 0xffffu);
    return (float)c.h;
}
__device__ __forceinline__ float hi_h(unsigned u) {
    union { unsigned short s; half_t h; } c; c.s = (unsigned short)(u >> 16);
    return (float)c.h;
}

// Scaled space: W = ALPHA*w, y_t = W[t]·x_t, h_t = 1/(1+2^{y_t}),
// W[t+1] = W[t] + h_t*cx_t,  cx_t = ALPHA*LR*r_t*x_t.
// Lookahead: y_{t+1} = u_t + h_t*d_t,  u_t = W[t]·x_{t+1},  d_t = cx_t·x_{t+1}.
// Jacobian: J_{t+1} = J_t + cx_t * f'(y_t) * (x_t^T J_t), f'(y) = -ln2*h(1-h).
__global__ void prep_kernel(const float* __restrict__ X,
                            const float* __restrict__ rewards,
                            float4* __restrict__ pk, float* __restrict__ dv,
                            int T, int Talloc) {
    int t = blockIdx.x * blockDim.x + threadIdx.x;
    if (t >= Talloc) return;
    if (t >= T) { pk[t] = make_float4(0.f, 0.f, 0.f, 0.f); dv[t] = 0.f; return; }
    int lo = t - (WINDOW_C - 1); if (lo < 0) lo = 0;
    float s = 0.0f;
    for (int k = lo; k <= t; ++k) s += rewards[k];
    float r = rewards[t] - s / (float)(t - lo + 1);
    float c = ALPHA * LR_C * r;
    float cx0 = c * X[2 * t];
    float cx1 = c * X[2 * t + 1];
    float xn0 = 0.0f, xn1 = 0.0f;
    if (t + 1 < T) { xn0 = X[2 * t + 2]; xn1 = X[2 * t + 3]; }
    pk[t] = make_float4(xn0, xn1, cx0, cx1);
    dv[t] = fmaf(cx1, xn1, cx0 * xn0);
}

// MODE 0: v = uniform ALPHA*Winit (written to vbuf); fine WITH J; writes F,J.
// MODE 1: v from vbuf; fine WITH J (true Newton); writes F,J.
// MODE 2: v from vbuf; linear fine; packed-fp16 OUT tree.
// MODE 3: v from vbuf; linear fine; writes F only (final chord correction).
template <int MODE>
__global__ __launch_bounds__(256, 4) void sweep_kernel(
    const float* __restrict__ Wg, const float* __restrict__ X,
    const float4* __restrict__ pk, const float* __restrict__ dv,
    float2* __restrict__ vbuf, float2* __restrict__ Fbuf,
    float4* __restrict__ Jbuf,
    int L, int Lpad, unsigned* __restrict__ partialU, int T, int TW2) {
    extern __shared__ char smem[];
    float4* lpk = (float4*)smem;
    float*  ldv = (float*)(smem + 16 * (size_t)Lpad);

    const int tid  = threadIdx.x;
    const int s    = blockIdx.x >> 1;
    const int half = blockIdx.x & 1;
    const int unit = half * 256 + tid;
    const int lane = tid & 63;
    const int wv   = tid >> 6;
    const int t0   = s * L;
    const bool WITHJ = (MODE == 0 || MODE == 1);

    // stage operands (issued first; completes during init)
    for (int k = wv; k * 64 < Lpad; k += 4)
        gld_lds16(pk + t0 + k * 64 + lane, lpk + k * 64);
    for (int k = wv; k * 64 < Lpad; k += 4)
        gld_lds4(dv + t0 + k * 64 + lane, ldv + k * 64);

    float W0, W1;
    if (MODE == 0) {
        W0 = ALPHA * Wg[2 * unit];
        W1 = ALPHA * Wg[2 * unit + 1];
        vbuf[(size_t)s * NH + unit] = make_float2(W0, W1);
    } else {
        float2 vv = vbuf[(size_t)s * NH + unit];
        W0 = vv.x; W1 = vv.y;
    }

    __builtin_amdgcn_s_waitcnt(0);
    __syncthreads();

    float x0 = 0.f, x1 = 0.f;
    if (t0 < T) { x0 = X[2 * t0]; x1 = X[2 * t0 + 1]; }
    float u = fmaf(W1, x1, W0 * x0);
    float h = 0.f, dpv = 0.f, cxp0 = 0.f, cxp1 = 0.f;
    float xa0 = 0.f, xa1 = 0.f, xb0 = x0, xb1 = x1;   // x_{t-1}, x_t carries
    float J00 = 1.f, J01 = 0.f, J10 = 0.f, J11 = 1.f;

    const int prow = half * 4 + wv;
    float4 pA[8], pB[8], dA[2], dB[2];
    float hh[8];

// J-update placed AFTER exp2 issue (fills trans-latency shadow); it reads
// h = h_{t-1}, xa = x_{t-1}, cxp = cx_{t-1}, all still live at that point.
#define BODY(Pq, Dq, TT)                                                      \
    {                                                                         \
        _Pragma("unroll")                                                     \
        for (int j = 0; j < 8; ++j) {                                         \
            float y = fmaf(h, dpv, u);                                        \
            float e = __builtin_amdgcn_exp2f(y);                              \
            if (WITHJ) {                                                      \
                float hm = fmaf(-h, h, h);                                    \
                float g = hm * -0.69314718055994531f;                         \
                float a0 = fmaf(xa1, J10, xa0 * J00);                         \
                float a1 = fmaf(xa1, J11, xa0 * J01);                         \
                float ga0 = g * a0, ga1 = g * a1;                             \
                J00 = fmaf(cxp0, ga0, J00); J01 = fmaf(cxp0, ga1, J01);       \
                J10 = fmaf(cxp1, ga0, J10); J11 = fmaf(cxp1, ga1, J11);       \
            }                                                                 \
            W0 = fmaf(h, cxp0, W0);                                           \
            W1 = fmaf(h, cxp1, W1);                                           \
            u = fmaf(W1, Pq[j].y, W0 * Pq[j].x);                              \
            h = __builtin_amdgcn_rcpf(1.0f + e);                              \
            hh[j] = h;                                                        \
            xa0 = xb0; xa1 = xb1; xb0 = Pq[j].x; xb1 = Pq[j].y;               \
            cxp0 = Pq[j].z; cxp1 = Pq[j].w; dpv = Dq[j >> 2][j & 3];          \
        }                                                                     \
        if (MODE == 2) {                                                      \
            unsigned pku[4];                                                  \
            _Pragma("unroll")                                                 \
            for (int q = 0; q < 4; ++q)                                       \
                pku[q] = pack_h2(hh[2 * q], hh[2 * q + 1]);                   \
            _Pragma("unroll")                                                 \
            for (int m = 1; m < WAVE; m <<= 1) {                              \
                _Pragma("unroll")                                             \
                for (int q = 0; q < 4; ++q)                                   \
                    pku[q] = pkadd(pku[q], __shfl_xor(pku[q], m, WAVE));      \
            }                                                                 \
            if (lane == 0) {                                                  \
                uint4 st = make_uint4(pku[0], pku[1], pku[2], pku[3]);        \
                *(uint4*)(partialU + (size_t)prow * TW2 + ((t0 + (TT)) >> 1)) = st; \
            }                                                                 \
        }                                                                     \
    }

    #pragma unroll
    for (int j = 0; j < 8; ++j) pA[j] = lpk[j];
    dA[0] = *(float4*)(ldv);     dA[1] = *(float4*)(ldv + 4);
    for (int s0 = 0; s0 < L; s0 += 16) {
        #pragma unroll
        for (int j = 0; j < 8; ++j) pB[j] = lpk[s0 + 8 + j];
        dB[0] = *(float4*)(ldv + s0 + 8); dB[1] = *(float4*)(ldv + s0 + 12);
        BODY(pA, dA, s0)
        if (s0 + 16 < L) {
            #pragma unroll
            for (int j = 0; j < 8; ++j) pA[j] = lpk[s0 + 16 + j];
            dA[0] = *(float4*)(ldv + s0 + 16); dA[1] = *(float4*)(ldv + s0 + 20);
        }
        BODY(pB, dB, s0 + 8)
    }
#undef BODY

    if (MODE != 2) {
        if (WITHJ) {
            // step L-1 J-update: after the loop, xa = x_{L-1}
            float hm = fmaf(-h, h, h);
            float g = hm * -0.69314718055994531f;
            float a0 = fmaf(xa1, J10, xa0 * J00);
            float a1 = fmaf(xa1, J11, xa0 * J01);
            float ga0 = g * a0, ga1 = g * a1;
            J00 = fmaf(cxp0, ga0, J00); J01 = fmaf(cxp0, ga1, J01);
            J10 = fmaf(cxp1, ga0, J10); J11 = fmaf(cxp1, ga1, J11);
            Jbuf[(size_t)s * NH + unit] = make_float4(J00, J01, J10, J11);
        }
        W0 = fmaf(h, cxp0, W0);
        W1 = fmaf(h, cxp1, W1);
        Fbuf[(size_t)s * NH + unit] = make_float2(W0, W1);
    }
}

// Parallel affine scan (Hillis-Steele) over 500 segments, one block per unit.
// Step i (i<NSEG-1): e_{i+1} = J_i e_i + (F_i - v_{i+1}), e_0 = 0.
// After inclusive scan, element i holds e_{i+1}; update v[i+1] += e_{i+1}.
__global__ __launch_bounds__(512) void scan_kernel(
    float2* __restrict__ vbuf, const float2* __restrict__ Fbuf,
    const float4* __restrict__ Jbuf) {
    __shared__ float4 As[512];
    __shared__ float2 bs[512];
    const int i = threadIdx.x;
    const int u = blockIdx.x;
    float2 vnext = make_float2(0.f, 0.f);
    if (i < NSEG - 1) {
        float4 Jm = Jbuf[(size_t)i * NH + u];
        float2 Fv = Fbuf[(size_t)i * NH + u];
        vnext = vbuf[(size_t)(i + 1) * NH + u];
        As[i] = Jm;
        bs[i] = make_float2(Fv.x - vnext.x, Fv.y - vnext.y);
    } else {
        As[i] = make_float4(1.f, 0.f, 0.f, 1.f);
        bs[i] = make_float2(0.f, 0.f);
    }
    __syncthreads();
    #pragma unroll
    for (int off = 1; off < 512; off <<= 1) {
        float4 Ai = As[i]; float2 bi = bs[i];
        float4 Ap = make_float4(1.f, 0.f, 0.f, 1.f);
        float2 bp = make_float2(0.f, 0.f);
        const bool act = (i >= off);
        if (act) { Ap = As[i - off]; bp = bs[i - off]; }
        __syncthreads();
        if (act) {
            float4 C;
            C.x = fmaf(Ai.y, Ap.z, Ai.x * Ap.x);
            C.y = fmaf(Ai.y, Ap.w, Ai.x * Ap.y);
            C.z = fmaf(Ai.w, Ap.z, Ai.z * Ap.x);
            C.w = fmaf(Ai.w, Ap.w, Ai.z * Ap.y);
            float2 nb;
            nb.x = fmaf(Ai.y, bp.y, fmaf(Ai.x, bp.x, bi.x));
            nb.y = fmaf(Ai.w, bp.y, fmaf(Ai.z, bp.x, bi.y));
            As[i] = C; bs[i] = nb;
        }
        __syncthreads();
    }
    if (i < NSEG - 1) {
        float2 e = bs[i];
        vbuf[(size_t)(i + 1) * NH + u] = make_float2(vnext.x + e.x, vnext.y + e.y);
    }
}

// Unpack + sum the 8 packed partial rows; one thread per t-pair.
__global__ void final_packed(const unsigned* __restrict__ pU,
                             float* __restrict__ out, int T, int TW2) {
    int p = blockIdx.x * blockDim.x + threadIdx.x;
    if (p >= (T + 1) / 2) return;
    float s0 = 0.f, s1 = 0.f;
    #pragma unroll
    for (int r = 0; r < 8; ++r) {
        unsigned v = pU[(size_t)r * TW2 + p];
        s0 += lo_h(v);
        s1 += hi_h(v);
    }
    const float inv = 1.0f / (float)NH;
    out[2 * p] = s0 * inv;
    if (2 * p + 1 < T) out[2 * p + 1] = s1 * inv;
}

extern "C" void kernel_launch(void* const* d_in, const int* in_sizes, int n_in,
                              void* d_out, int out_size, void* d_ws, size_t ws_size,
                              hipStream_t stream) {
    const float* X       = (const float*)d_in[0];
    const float* rewards = (const float*)d_in[1];
    const float* Winit   = (const float*)d_in[2];
    float* out = (float*)d_out;
    const int T = in_sizes[1];

    const int L  = (((T + NSEG - 1) / NSEG) + 15) & ~15;  // seg length, %16==0
    const int TW = NSEG * L;
    const int TW2 = TW / 2;
    const int Lpad = ((L + 63) >> 6) << 6;
    const int Talloc = TW + Lpad + 64;

    char* w = (char*)d_ws;
    float4*   pk  = (float4*)w;                w += 16ull * (size_t)Talloc;
    float*    dvp = (float*)w;                 w += 4ull * (size_t)Talloc;
    float2*   v   = (float2*)w;                w += 8ull * NSEG * NH;    // 2 MB
    float2*   F   = (float2*)w;                w += 8ull * NSEG * NH;    // 2 MB
    float4*   J   = (float4*)w;                w += 16ull * NSEG * NH;   // 4 MB
    unsigned* partialU = (unsigned*)w;         // 8 * TW2 u32 (~1.7 MB)

    prep_kernel<<<(Talloc + 255) / 256, 256, 0, stream>>>(X, rewards, pk, dvp, T, Talloc);

    const size_t smem = (size_t)Lpad * 20;
    // true Newton sweeps 0..KN-2 (fresh J each); final correction (KN-1) is a
    // lite sweep (F only) whose scan reuses the previous sweep's J (chord at
    // near-convergence, second-order error).
    sweep_kernel<0><<<2 * NSEG, 256, smem, stream>>>(
        Winit, X, pk, dvp, v, F, J, L, Lpad, nullptr, T, TW2);
    scan_kernel<<<NH, 512, 0, stream>>>(v, F, J);
    for (int q = 1; q < KN - 1; ++q) {
        sweep_kernel<1><<<2 * NSEG, 256, smem, stream>>>(
            Winit, X, pk, dvp, v, F, J, L, Lpad, nullptr, T, TW2);
        scan_kernel<<<NH, 512, 0, stream>>>(v, F, J);
    }
    sweep_kernel<3><<<2 * NSEG, 256, smem, stream>>>(
        Winit, X, pk, dvp, v, F, J, L, Lpad, nullptr, T, TW2);
    scan_kernel<<<NH, 512, 0, stream>>>(v, F, J);
    sweep_kernel<2><<<2 * NSEG, 256, smem, stream>>>(
        Winit, X, pk, dvp, v, F, J, L, Lpad, partialU, T, TW2);

    final_packed<<<((T + 1) / 2 + 255) / 256, 256, 0, stream>>>(partialU, out, T, TW2);
}

// Round 23
// 276.888 us; speedup vs baseline: 1.3719x; 1.3719x over previous
//
#include <hip/hip_runtime.h>
#include <math.h>

#define LR_C 0.1f
#define WINDOW_C 10
#define NH 512
#define WAVE 64
#define ALPHA (-1.44269504088896340736f)  // -log2(e)
#define NSEG 250
#define NEWT 4   // Newton sweeps (fresh J); calib: 4 Newton -> eps ~0.08
#define CHORD 2  // chord updates with last J: eps 0.08 -> ~6e-3 -> ~5e-4

typedef _Float16 half_t;
typedef __fp16 fp16x2_t __attribute__((ext_vector_type(2)));

__device__ __forceinline__ void gld_lds16(const void* g, void* l) {
    __builtin_amdgcn_global_load_lds((const __attribute__((address_space(1))) void*)g,
                                     (__attribute__((address_space(3))) void*)l, 16, 0, 0);
}
__device__ __forceinline__ void gld_lds4(const void* g, void* l) {
    __builtin_amdgcn_global_load_lds((const __attribute__((address_space(1))) void*)g,
                                     (__attribute__((address_space(3))) void*)l, 4, 0, 0);
}
__device__ __forceinline__ unsigned pack_h2(float a, float b) {
    union { fp16x2_t h; unsigned u; } c;
    c.h = __builtin_amdgcn_cvt_pkrtz(a, b);
    return c.u;
}
__device__ __forceinline__ unsigned pkadd(unsigned a, unsigned b) {
    union { fp16x2_t h; unsigned u; } x, y;
    x.u = a; y.u = b;
    x.h = x.h + y.h;   // v_pk_add_f16
    return x.u;
}
__device__ __forceinline__ float lo_h(unsigned u) {
    union { unsigned short s; half_t h; } c; c.s = (unsigned short)(u & 0xffffu);
    return (float)c.h;
}
__device__ __forceinline__ float hi_h(unsigned u) {
    union { unsigned short s; half_t h; } c; c.s = (unsigned short)(u >> 16);
    return (float)c.h;
}

// Scaled space: W = ALPHA*w, y_t = W[t]·x_t, h_t = 1/(1+2^{y_t}),
// W[t+1] = W[t] + h_t*cx_t,  cx_t = ALPHA*LR*r_t*x_t.
// Lookahead: y_{t+1} = u_t + h_t*d_t,  u_t = W[t]·x_{t+1},  d_t = cx_t·x_{t+1}.
// Jacobian: J_{t+1} = J_t + cx_t * f'(y_t) * (x_t^T J_t), f'(y) = -ln2*h(1-h).
__global__ void prep_kernel(const float* __restrict__ X,
                            const float* __restrict__ rewards,
                            float4* __restrict__ pk, float* __restrict__ dv,
                            int T, int Talloc) {
    int t = blockIdx.x * blockDim.x + threadIdx.x;
    if (t >= Talloc) return;
    if (t >= T) { pk[t] = make_float4(0.f, 0.f, 0.f, 0.f); dv[t] = 0.f; return; }
    int lo = t - (WINDOW_C - 1); if (lo < 0) lo = 0;
    float s = 0.0f;
    for (int k = lo; k <= t; ++k) s += rewards[k];
    float r = rewards[t] - s / (float)(t - lo + 1);
    float c = ALPHA * LR_C * r;
    float cx0 = c * X[2 * t];
    float cx1 = c * X[2 * t + 1];
    float xn0 = 0.0f, xn1 = 0.0f;
    if (t + 1 < T) { xn0 = X[2 * t + 2]; xn1 = X[2 * t + 3]; }
    pk[t] = make_float4(xn0, xn1, cx0, cx1);
    dv[t] = fmaf(cx1, xn1, cx0 * xn0);
}

// MODE 0: v = uniform ALPHA*Winit (written to vbuf); fine WITH J; writes F,J.
// MODE 1: v from vbuf; fine WITH J (true Newton); writes F,J.
// MODE 2: v from vbuf; linear fine; packed-fp16 OUT tree.
// MODE 3: v from vbuf; linear fine; writes F only (chord correction).
template <int MODE>
__global__ __launch_bounds__(256, 2) void sweep_kernel(
    const float* __restrict__ Wg, const float* __restrict__ X,
    const float4* __restrict__ pk, const float* __restrict__ dv,
    float2* __restrict__ vbuf, float2* __restrict__ Fbuf,
    float4* __restrict__ Jbuf,
    int L, int Lpad, unsigned* __restrict__ partialU, int T, int TW2) {
    extern __shared__ char smem[];
    float4* lpk = (float4*)smem;
    float*  ldv = (float*)(smem + 16 * (size_t)Lpad);

    const int tid  = threadIdx.x;
    const int s    = blockIdx.x >> 1;
    const int half = blockIdx.x & 1;
    const int unit = half * 256 + tid;
    const int lane = tid & 63;
    const int wv   = tid >> 6;
    const int t0   = s * L;
    const bool WITHJ = (MODE == 0 || MODE == 1);

    // stage operands (issued first; completes during init)
    for (int k = wv; k * 64 < Lpad; k += 4)
        gld_lds16(pk + t0 + k * 64 + lane, lpk + k * 64);
    for (int k = wv; k * 64 < Lpad; k += 4)
        gld_lds4(dv + t0 + k * 64 + lane, ldv + k * 64);

    float W0, W1;
    if (MODE == 0) {
        W0 = ALPHA * Wg[2 * unit];
        W1 = ALPHA * Wg[2 * unit + 1];
        vbuf[(size_t)s * NH + unit] = make_float2(W0, W1);
    } else {
        float2 vv = vbuf[(size_t)s * NH + unit];
        W0 = vv.x; W1 = vv.y;
    }

    __builtin_amdgcn_s_waitcnt(0);
    __syncthreads();

    float x0 = 0.f, x1 = 0.f;
    if (t0 < T) { x0 = X[2 * t0]; x1 = X[2 * t0 + 1]; }
    float u = fmaf(W1, x1, W0 * x0);
    float h = 0.f, dpv = 0.f, cxp0 = 0.f, cxp1 = 0.f;
    float xa0 = 0.f, xa1 = 0.f, xb0 = x0, xb1 = x1;   // x_{t-1}, x_t carries
    float J00 = 1.f, J01 = 0.f, J10 = 0.f, J11 = 1.f;

    const int prow = half * 4 + wv;
    float4 pA[8], pB[8], dA[2], dB[2];
    float hh[8];

// J-update placed AFTER exp2 issue (fills trans-latency shadow); it reads
// h = h_{t-1}, xa = x_{t-1}, cxp = cx_{t-1}, all still live at that point.
#define BODY(Pq, Dq, TT)                                                      \
    {                                                                         \
        _Pragma("unroll")                                                     \
        for (int j = 0; j < 8; ++j) {                                         \
            float y = fmaf(h, dpv, u);                                        \
            float e = __builtin_amdgcn_exp2f(y);                              \
            if (WITHJ) {                                                      \
                float hm = fmaf(-h, h, h);                                    \
                float g = hm * -0.69314718055994531f;                         \
                float a0 = fmaf(xa1, J10, xa0 * J00);                         \
                float a1 = fmaf(xa1, J11, xa0 * J01);                         \
                float ga0 = g * a0, ga1 = g * a1;                             \
                J00 = fmaf(cxp0, ga0, J00); J01 = fmaf(cxp0, ga1, J01);       \
                J10 = fmaf(cxp1, ga0, J10); J11 = fmaf(cxp1, ga1, J11);       \
            }                                                                 \
            W0 = fmaf(h, cxp0, W0);                                           \
            W1 = fmaf(h, cxp1, W1);                                           \
            u = fmaf(W1, Pq[j].y, W0 * Pq[j].x);                              \
            h = __builtin_amdgcn_rcpf(1.0f + e);                              \
            hh[j] = h;                                                        \
            xa0 = xb0; xa1 = xb1; xb0 = Pq[j].x; xb1 = Pq[j].y;               \
            cxp0 = Pq[j].z; cxp1 = Pq[j].w; dpv = Dq[j >> 2][j & 3];          \
        }                                                                     \
        if (MODE == 2) {                                                      \
            unsigned pku[4];                                                  \
            _Pragma("unroll")                                                 \
            for (int q = 0; q < 4; ++q)                                       \
                pku[q] = pack_h2(hh[2 * q], hh[2 * q + 1]);                   \
            _Pragma("unroll")                                                 \
            for (int m = 1; m < WAVE; m <<= 1) {                              \
                _Pragma("unroll")                                             \
                for (int q = 0; q < 4; ++q)                                   \
                    pku[q] = pkadd(pku[q], __shfl_xor(pku[q], m, WAVE));      \
            }                                                                 \
            if (lane == 0) {                                                  \
                uint4 st = make_uint4(pku[0], pku[1], pku[2], pku[3]);        \
                *(uint4*)(partialU + (size_t)prow * TW2 + ((t0 + (TT)) >> 1)) = st; \
            }                                                                 \
        }                                                                     \
    }

    #pragma unroll
    for (int j = 0; j < 8; ++j) pA[j] = lpk[j];
    dA[0] = *(float4*)(ldv);     dA[1] = *(float4*)(ldv + 4);
    for (int s0 = 0; s0 < L; s0 += 16) {
        #pragma unroll
        for (int j = 0; j < 8; ++j) pB[j] = lpk[s0 + 8 + j];
        dB[0] = *(float4*)(ldv + s0 + 8); dB[1] = *(float4*)(ldv + s0 + 12);
        BODY(pA, dA, s0)
        if (s0 + 16 < L) {
            #pragma unroll
            for (int j = 0; j < 8; ++j) pA[j] = lpk[s0 + 16 + j];
            dA[0] = *(float4*)(ldv + s0 + 16); dA[1] = *(float4*)(ldv + s0 + 20);
        }
        BODY(pB, dB, s0 + 8)
    }
#undef BODY

    if (MODE != 2) {
        if (WITHJ) {
            // step L-1 J-update: after the loop, xa = x_{L-1}
            float hm = fmaf(-h, h, h);
            float g = hm * -0.69314718055994531f;
            float a0 = fmaf(xa1, J10, xa0 * J00);
            float a1 = fmaf(xa1, J11, xa0 * J01);
            float ga0 = g * a0, ga1 = g * a1;
            J00 = fmaf(cxp0, ga0, J00); J01 = fmaf(cxp0, ga1, J01);
            J10 = fmaf(cxp1, ga0, J10); J11 = fmaf(cxp1, ga1, J11);
            Jbuf[(size_t)s * NH + unit] = make_float4(J00, J01, J10, J11);
        }
        W0 = fmaf(h, cxp0, W0);
        W1 = fmaf(h, cxp1, W1);
        Fbuf[(size_t)s * NH + unit] = make_float2(W0, W1);
    }
}

// Parallel affine scan (Hillis-Steele) over segments, one block per unit.
// Step i (i<NSEG-1): e_{i+1} = J_i e_i + (F_i - v_{i+1}), e_0 = 0.
// After inclusive scan, element i holds e_{i+1}; update v[i+1] += e_{i+1}.
__global__ __launch_bounds__(256) void scan_kernel(
    float2* __restrict__ vbuf, const float2* __restrict__ Fbuf,
    const float4* __restrict__ Jbuf) {
    __shared__ float4 As[256];
    __shared__ float2 bs[256];
    const int i = threadIdx.x;
    const int u = blockIdx.x;
    float2 vnext = make_float2(0.f, 0.f);
    if (i < NSEG - 1) {
        float4 Jm = Jbuf[(size_t)i * NH + u];
        float2 Fv = Fbuf[(size_t)i * NH + u];
        vnext = vbuf[(size_t)(i + 1) * NH + u];
        As[i] = Jm;
        bs[i] = make_float2(Fv.x - vnext.x, Fv.y - vnext.y);
    } else {
        As[i] = make_float4(1.f, 0.f, 0.f, 1.f);
        bs[i] = make_float2(0.f, 0.f);
    }
    __syncthreads();
    #pragma unroll
    for (int off = 1; off < 256; off <<= 1) {
        float4 Ai = As[i]; float2 bi = bs[i];
        float4 Ap = make_float4(1.f, 0.f, 0.f, 1.f);
        float2 bp = make_float2(0.f, 0.f);
        const bool act = (i >= off);
        if (act) { Ap = As[i - off]; bp = bs[i - off]; }
        __syncthreads();
        if (act) {
            float4 C;
            C.x = fmaf(Ai.y, Ap.z, Ai.x * Ap.x);
            C.y = fmaf(Ai.y, Ap.w, Ai.x * Ap.y);
            C.z = fmaf(Ai.w, Ap.z, Ai.z * Ap.x);
            C.w = fmaf(Ai.w, Ap.w, Ai.z * Ap.y);
            float2 nb;
            nb.x = fmaf(Ai.y, bp.y, fmaf(Ai.x, bp.x, bi.x));
            nb.y = fmaf(Ai.w, bp.y, fmaf(Ai.z, bp.x, bi.y));
            As[i] = C; bs[i] = nb;
        }
        __syncthreads();
    }
    if (i < NSEG - 1) {
        float2 e = bs[i];
        vbuf[(size_t)(i + 1) * NH + u] = make_float2(vnext.x + e.x, vnext.y + e.y);
    }
}

// Unpack + sum the 8 packed partial rows; one thread per t-pair.
__global__ void final_packed(const unsigned* __restrict__ pU,
                             float* __restrict__ out, int T, int TW2) {
    int p = blockIdx.x * blockDim.x + threadIdx.x;
    if (p >= (T + 1) / 2) return;
    float s0 = 0.f, s1 = 0.f;
    #pragma unroll
    for (int r = 0; r < 8; ++r) {
        unsigned v = pU[(size_t)r * TW2 + p];
        s0 += lo_h(v);
        s1 += hi_h(v);
    }
    const float inv = 1.0f / (float)NH;
    out[2 * p] = s0 * inv;
    if (2 * p + 1 < T) out[2 * p + 1] = s1 * inv;
}

extern "C" void kernel_launch(void* const* d_in, const int* in_sizes, int n_in,
                              void* d_out, int out_size, void* d_ws, size_t ws_size,
                              hipStream_t stream) {
    const float* X       = (const float*)d_in[0];
    const float* rewards = (const float*)d_in[1];
    const float* Winit   = (const float*)d_in[2];
    float* out = (float*)d_out;
    const int T = in_sizes[1];

    const int L  = (((T + NSEG - 1) / NSEG) + 15) & ~15;  // seg length, %16==0
    const int TW = NSEG * L;
    const int TW2 = TW / 2;
    const int Lpad = ((L + 63) >> 6) << 6;
    const int Talloc = TW + Lpad + 64;

    char* w = (char*)d_ws;
    float4*   pk  = (float4*)w;                w += 16ull * (size_t)Talloc;
    float*    dvp = (float*)w;                 w += 4ull * (size_t)Talloc;
    float2*   v   = (float2*)w;                w += 8ull * NSEG * NH;    // 1 MB
    float2*   F   = (float2*)w;                w += 8ull * NSEG * NH;    // 1 MB
    float4*   J   = (float4*)w;                w += 16ull * NSEG * NH;   // 2 MB
    unsigned* partialU = (unsigned*)w;         // 8 * TW2 u32 (~1.6 MB)

    prep_kernel<<<(Talloc + 255) / 256, 256, 0, stream>>>(X, rewards, pk, dvp, T, Talloc);

    const size_t smem = (size_t)Lpad * 20;
    // 4 true-Newton updates (fresh J each), then 2 chord updates (lite
    // sweeps reusing sweep-3's J), then the OUT pass.
    sweep_kernel<0><<<2 * NSEG, 256, smem, stream>>>(
        Winit, X, pk, dvp, v, F, J, L, Lpad, nullptr, T, TW2);
    scan_kernel<<<NH, 256, 0, stream>>>(v, F, J);
    for (int q = 1; q < NEWT; ++q) {
        sweep_kernel<1><<<2 * NSEG, 256, smem, stream>>>(
            Winit, X, pk, dvp, v, F, J, L, Lpad, nullptr, T, TW2);
        scan_kernel<<<NH, 256, 0, stream>>>(v, F, J);
    }
    for (int q = 0; q < CHORD; ++q) {
        sweep_kernel<3><<<2 * NSEG, 256, smem, stream>>>(
            Winit, X, pk, dvp, v, F, J, L, Lpad, nullptr, T, TW2);
        scan_kernel<<<NH, 256, 0, stream>>>(v, F, J);
    }
    sweep_kernel<2><<<2 * NSEG, 256, smem, stream>>>(
        Winit, X, pk, dvp, v, F, J, L, Lpad, partialU, T, TW2);

    final_packed<<<((T + 1) / 2 + 255) / 256, 256, 0, stream>>>(partialU, out, T, TW2);
}

// Round 24
// 248.923 us; speedup vs baseline: 1.5260x; 1.1123x over previous
//
#include <hip/hip_runtime.h>
#include <math.h>

#define LR_C 0.1f
#define WINDOW_C 10
#define NH 512
#define WAVE 64
#define ALPHA (-1.44269504088896340736f)  // -log2(e)
#define NSEG 250
#define NEWT 4   // Newton sweeps (fresh J); calib: 4 updates -> eps ~0.08
#define CHORD 1  // chord updates: ratio in [0.08, 0.22] -> eps5 in [0.006, 0.018]

typedef _Float16 half_t;
typedef __fp16 fp16x2_t __attribute__((ext_vector_type(2)));

__device__ __forceinline__ void gld_lds16(const void* g, void* l) {
    __builtin_amdgcn_global_load_lds((const __attribute__((address_space(1))) void*)g,
                                     (__attribute__((address_space(3))) void*)l, 16, 0, 0);
}
__device__ __forceinline__ void gld_lds4(const void* g, void* l) {
    __builtin_amdgcn_global_load_lds((const __attribute__((address_space(1))) void*)g,
                                     (__attribute__((address_space(3))) void*)l, 4, 0, 0);
}
__device__ __forceinline__ unsigned pack_h2(float a, float b) {
    union { fp16x2_t h; unsigned u; } c;
    c.h = __builtin_amdgcn_cvt_pkrtz(a, b);
    return c.u;
}
__device__ __forceinline__ unsigned pkadd(unsigned a, unsigned b) {
    union { fp16x2_t h; unsigned u; } x, y;
    x.u = a; y.u = b;
    x.h = x.h + y.h;   // v_pk_add_f16
    return x.u;
}
__device__ __forceinline__ float lo_h(unsigned u) {
    union { unsigned short s; half_t h; } c; c.s = (unsigned short)(u & 0xffffu);
    return (float)c.h;
}
__device__ __forceinline__ float hi_h(unsigned u) {
    union { unsigned short s; half_t h; } c; c.s = (unsigned short)(u >> 16);
    return (float)c.h;
}

// Scaled space: W = ALPHA*w, y_t = W[t]·x_t, h_t = 1/(1+2^{y_t}),
// W[t+1] = W[t] + h_t*cx_t,  cx_t = ALPHA*LR*r_t*x_t.
// Lookahead: y_{t+1} = u_t + h_t*d_t,  u_t = W[t]·x_{t+1},  d_t = cx_t·x_{t+1}.
// Jacobian: J_{t+1} = J_t + cx_t * f'(y_t) * (x_t^T J_t), f'(y) = -ln2*h(1-h).
__global__ void prep_kernel(const float* __restrict__ X,
                            const float* __restrict__ rewards,
                            float4* __restrict__ pk, float* __restrict__ dv,
                            int T, int Talloc) {
    int t = blockIdx.x * blockDim.x + threadIdx.x;
    if (t >= Talloc) return;
    if (t >= T) { pk[t] = make_float4(0.f, 0.f, 0.f, 0.f); dv[t] = 0.f; return; }
    int lo = t - (WINDOW_C - 1); if (lo < 0) lo = 0;
    float s = 0.0f;
    for (int k = lo; k <= t; ++k) s += rewards[k];
    float r = rewards[t] - s / (float)(t - lo + 1);
    float c = ALPHA * LR_C * r;
    float cx0 = c * X[2 * t];
    float cx1 = c * X[2 * t + 1];
    float xn0 = 0.0f, xn1 = 0.0f;
    if (t + 1 < T) { xn0 = X[2 * t + 2]; xn1 = X[2 * t + 3]; }
    pk[t] = make_float4(xn0, xn1, cx0, cx1);
    dv[t] = fmaf(cx1, xn1, cx0 * xn0);
}

// MODE 0: v = uniform ALPHA*Winit (written to vbuf); fine WITH J; writes F,J.
// MODE 1: v from vbuf; fine WITH J (true Newton); writes F,J.
// MODE 2: v from vbuf; linear fine; packed-fp16 OUT tree.
// MODE 3: v from vbuf; linear fine; writes F only (chord correction).
template <int MODE>
__global__ __launch_bounds__(256, 2) void sweep_kernel(
    const float* __restrict__ Wg, const float* __restrict__ X,
    const float4* __restrict__ pk, const float* __restrict__ dv,
    float2* __restrict__ vbuf, float2* __restrict__ Fbuf,
    float4* __restrict__ Jbuf,
    int L, int Lpad, unsigned* __restrict__ partialU, int T, int TW2) {
    extern __shared__ char smem[];
    float4* lpk = (float4*)smem;
    float*  ldv = (float*)(smem + 16 * (size_t)Lpad);

    const int tid  = threadIdx.x;
    const int s    = blockIdx.x >> 1;
    const int half = blockIdx.x & 1;
    const int unit = half * 256 + tid;
    const int lane = tid & 63;
    const int wv   = tid >> 6;
    const int t0   = s * L;
    const bool WITHJ = (MODE == 0 || MODE == 1);

    // stage operands (issued first; completes during init)
    for (int k = wv; k * 64 < Lpad; k += 4)
        gld_lds16(pk + t0 + k * 64 + lane, lpk + k * 64);
    for (int k = wv; k * 64 < Lpad; k += 4)
        gld_lds4(dv + t0 + k * 64 + lane, ldv + k * 64);

    float W0, W1;
    if (MODE == 0) {
        W0 = ALPHA * Wg[2 * unit];
        W1 = ALPHA * Wg[2 * unit + 1];
        vbuf[(size_t)s * NH + unit] = make_float2(W0, W1);
    } else {
        float2 vv = vbuf[(size_t)s * NH + unit];
        W0 = vv.x; W1 = vv.y;
    }

    __builtin_amdgcn_s_waitcnt(0);
    __syncthreads();

    float x0 = 0.f, x1 = 0.f;
    if (t0 < T) { x0 = X[2 * t0]; x1 = X[2 * t0 + 1]; }
    float u = fmaf(W1, x1, W0 * x0);
    float h = 0.f, dpv = 0.f, cxp0 = 0.f, cxp1 = 0.f;
    float xa0 = 0.f, xa1 = 0.f, xb0 = x0, xb1 = x1;   // x_{t-1}, x_t carries
    float J00 = 1.f, J01 = 0.f, J10 = 0.f, J11 = 1.f;

    const int prow = half * 4 + wv;
    float4 pA[8], pB[8], dA[2], dB[2];
    float hh[8];

// J-update placed AFTER exp2 issue (fills trans-latency shadow); it reads
// h = h_{t-1}, xa = x_{t-1}, cxp = cx_{t-1}, all still live at that point.
#define BODY(Pq, Dq, TT)                                                      \
    {                                                                         \
        _Pragma("unroll")                                                     \
        for (int j = 0; j < 8; ++j) {                                         \
            float y = fmaf(h, dpv, u);                                        \
            float e = __builtin_amdgcn_exp2f(y);                              \
            if (WITHJ) {                                                      \
                float hm = fmaf(-h, h, h);                                    \
                float g = hm * -0.69314718055994531f;                         \
                float a0 = fmaf(xa1, J10, xa0 * J00);                         \
                float a1 = fmaf(xa1, J11, xa0 * J01);                         \
                float ga0 = g * a0, ga1 = g * a1;                             \
                J00 = fmaf(cxp0, ga0, J00); J01 = fmaf(cxp0, ga1, J01);       \
                J10 = fmaf(cxp1, ga0, J10); J11 = fmaf(cxp1, ga1, J11);       \
            }                                                                 \
            W0 = fmaf(h, cxp0, W0);                                           \
            W1 = fmaf(h, cxp1, W1);                                           \
            u = fmaf(W1, Pq[j].y, W0 * Pq[j].x);                              \
            h = __builtin_amdgcn_rcpf(1.0f + e);                              \
            hh[j] = h;                                                        \
            xa0 = xb0; xa1 = xb1; xb0 = Pq[j].x; xb1 = Pq[j].y;               \
            cxp0 = Pq[j].z; cxp1 = Pq[j].w; dpv = Dq[j >> 2][j & 3];          \
        }                                                                     \
        if (MODE == 2) {                                                      \
            unsigned pku[4];                                                  \
            _Pragma("unroll")                                                 \
            for (int q = 0; q < 4; ++q)                                       \
                pku[q] = pack_h2(hh[2 * q], hh[2 * q + 1]);                   \
            _Pragma("unroll")                                                 \
            for (int m = 1; m < WAVE; m <<= 1) {                              \
                _Pragma("unroll")                                             \
                for (int q = 0; q < 4; ++q)                                   \
                    pku[q] = pkadd(pku[q], __shfl_xor(pku[q], m, WAVE));      \
            }                                                                 \
            if (lane == 0) {                                                  \
                uint4 st = make_uint4(pku[0], pku[1], pku[2], pku[3]);        \
                *(uint4*)(partialU + (size_t)prow * TW2 + ((t0 + (TT)) >> 1)) = st; \
            }                                                                 \
        }                                                                     \
    }

    #pragma unroll
    for (int j = 0; j < 8; ++j) pA[j] = lpk[j];
    dA[0] = *(float4*)(ldv);     dA[1] = *(float4*)(ldv + 4);
    for (int s0 = 0; s0 < L; s0 += 16) {
        #pragma unroll
        for (int j = 0; j < 8; ++j) pB[j] = lpk[s0 + 8 + j];
        dB[0] = *(float4*)(ldv + s0 + 8); dB[1] = *(float4*)(ldv + s0 + 12);
        BODY(pA, dA, s0)
        if (s0 + 16 < L) {
            #pragma unroll
            for (int j = 0; j < 8; ++j) pA[j] = lpk[s0 + 16 + j];
            dA[0] = *(float4*)(ldv + s0 + 16); dA[1] = *(float4*)(ldv + s0 + 20);
        }
        BODY(pB, dB, s0 + 8)
    }
#undef BODY

    if (MODE != 2) {
        if (WITHJ) {
            // step L-1 J-update: after the loop, xa = x_{L-1}
            float hm = fmaf(-h, h, h);
            float g = hm * -0.69314718055994531f;
            float a0 = fmaf(xa1, J10, xa0 * J00);
            float a1 = fmaf(xa1, J11, xa0 * J01);
            float ga0 = g * a0, ga1 = g * a1;
            J00 = fmaf(cxp0, ga0, J00); J01 = fmaf(cxp0, ga1, J01);
            J10 = fmaf(cxp1, ga0, J10); J11 = fmaf(cxp1, ga1, J11);
            Jbuf[(size_t)s * NH + unit] = make_float4(J00, J01, J10, J11);
        }
        W0 = fmaf(h, cxp0, W0);
        W1 = fmaf(h, cxp1, W1);
        Fbuf[(size_t)s * NH + unit] = make_float2(W0, W1);
    }
}

// Parallel affine scan (Hillis-Steele) over segments, one block per unit.
// Step i (i<NSEG-1): e_{i+1} = J_i e_i + (F_i - v_{i+1}), e_0 = 0.
// After inclusive scan, element i holds e_{i+1}; update v[i+1] += e_{i+1}.
__global__ __launch_bounds__(256) void scan_kernel(
    float2* __restrict__ vbuf, const float2* __restrict__ Fbuf,
    const float4* __restrict__ Jbuf) {
    __shared__ float4 As[256];
    __shared__ float2 bs[256];
    const int i = threadIdx.x;
    const int u = blockIdx.x;
    float2 vnext = make_float2(0.f, 0.f);
    if (i < NSEG - 1) {
        float4 Jm = Jbuf[(size_t)i * NH + u];
        float2 Fv = Fbuf[(size_t)i * NH + u];
        vnext = vbuf[(size_t)(i + 1) * NH + u];
        As[i] = Jm;
        bs[i] = make_float2(Fv.x - vnext.x, Fv.y - vnext.y);
    } else {
        As[i] = make_float4(1.f, 0.f, 0.f, 1.f);
        bs[i] = make_float2(0.f, 0.f);
    }
    __syncthreads();
    #pragma unroll
    for (int off = 1; off < 256; off <<= 1) {
        float4 Ai = As[i]; float2 bi = bs[i];
        float4 Ap = make_float4(1.f, 0.f, 0.f, 1.f);
        float2 bp = make_float2(0.f, 0.f);
        const bool act = (i >= off);
        if (act) { Ap = As[i - off]; bp = bs[i - off]; }
        __syncthreads();
        if (act) {
            float4 C;
            C.x = fmaf(Ai.y, Ap.z, Ai.x * Ap.x);
            C.y = fmaf(Ai.y, Ap.w, Ai.x * Ap.y);
            C.z = fmaf(Ai.w, Ap.z, Ai.z * Ap.x);
            C.w = fmaf(Ai.w, Ap.w, Ai.z * Ap.y);
            float2 nb;
            nb.x = fmaf(Ai.y, bp.y, fmaf(Ai.x, bp.x, bi.x));
            nb.y = fmaf(Ai.w, bp.y, fmaf(Ai.z, bp.x, bi.y));
            As[i] = C; bs[i] = nb;
        }
        __syncthreads();
    }
    if (i < NSEG - 1) {
        float2 e = bs[i];
        vbuf[(size_t)(i + 1) * NH + u] = make_float2(vnext.x + e.x, vnext.y + e.y);
    }
}

// Unpack + sum the 8 packed partial rows; one thread per t-pair.
__global__ void final_packed(const unsigned* __restrict__ pU,
                             float* __restrict__ out, int T, int TW2) {
    int p = blockIdx.x * blockDim.x + threadIdx.x;
    if (p >= (T + 1) / 2) return;
    float s0 = 0.f, s1 = 0.f;
    #pragma unroll
    for (int r = 0; r < 8; ++r) {
        unsigned v = pU[(size_t)r * TW2 + p];
        s0 += lo_h(v);
        s1 += hi_h(v);
    }
    const float inv = 1.0f / (float)NH;
    out[2 * p] = s0 * inv;
    if (2 * p + 1 < T) out[2 * p + 1] = s1 * inv;
}

extern "C" void kernel_launch(void* const* d_in, const int* in_sizes, int n_in,
                              void* d_out, int out_size, void* d_ws, size_t ws_size,
                              hipStream_t stream) {
    const float* X       = (const float*)d_in[0];
    const float* rewards = (const float*)d_in[1];
    const float* Winit   = (const float*)d_in[2];
    float* out = (float*)d_out;
    const int T = in_sizes[1];

    const int L  = (((T + NSEG - 1) / NSEG) + 15) & ~15;  // seg length, %16==0
    const int TW = NSEG * L;
    const int TW2 = TW / 2;
    const int Lpad = ((L + 63) >> 6) << 6;
    const int Talloc = TW + Lpad + 64;

    char* w = (char*)d_ws;
    float4*   pk  = (float4*)w;                w += 16ull * (size_t)Talloc;
    float*    dvp = (float*)w;                 w += 4ull * (size_t)Talloc;
    float2*   v   = (float2*)w;                w += 8ull * NSEG * NH;    // 1 MB
    float2*   F   = (float2*)w;                w += 8ull * NSEG * NH;    // 1 MB
    float4*   J   = (float4*)w;                w += 16ull * NSEG * NH;   // 2 MB
    unsigned* partialU = (unsigned*)w;         // 8 * TW2 u32 (~1.6 MB)

    prep_kernel<<<(Talloc + 255) / 256, 256, 0, stream>>>(X, rewards, pk, dvp, T, Talloc);

    const size_t smem = (size_t)Lpad * 20;
    // 4 true-Newton updates (fresh J each), 1 chord update (lite sweep,
    // reusing sweep-3's J), then the OUT pass.
    sweep_kernel<0><<<2 * NSEG, 256, smem, stream>>>(
        Winit, X, pk, dvp, v, F, J, L, Lpad, nullptr, T, TW2);
    scan_kernel<<<NH, 256, 0, stream>>>(v, F, J);
    for (int q = 1; q < NEWT; ++q) {
        sweep_kernel<1><<<2 * NSEG, 256, smem, stream>>>(
            Winit, X, pk, dvp, v, F, J, L, Lpad, nullptr, T, TW2);
        scan_kernel<<<NH, 256, 0, stream>>>(v, F, J);
    }
    for (int q = 0; q < CHORD; ++q) {
        sweep_kernel<3><<<2 * NSEG, 256, smem, stream>>>(
            Winit, X, pk, dvp, v, F, J, L, Lpad, nullptr, T, TW2);
        scan_kernel<<<NH, 256, 0, stream>>>(v, F, J);
    }
    sweep_kernel<2><<<2 * NSEG, 256, smem, stream>>>(
        Winit, X, pk, dvp, v, F, J, L, Lpad, partialU, T, TW2);

    final_packed<<<((T + 1) / 2 + 255) / 256, 256, 0, stream>>>(partialU, out, T, TW2);
}